// Round 2
// baseline (873.508 us; speedup 1.0000x reference)
//
#include <hip/hip_runtime.h>

#define D_   32
#define H_   256
#define W_   256
#define HW_  (H_ * W_)
#define DHW_ (D_ * H_ * W_)   // 2097152
#define V_   40000
#define CIN  16
#define COUT 32
#define P_   32
#define EPS_ 1e-5f

#define TD 2
#define TH 8
#define TW 32
#define NTX (W_ / TW)          // 8
#define NTY (H_ / TH)          // 32
#define NTZ (D_ / TD)          // 16
#define NT  (NTX * NTY * NTZ)  // 4096 tiles
#define TPOS (TD * TH * TW)    // 512
#define OH 8                   // channels per block (quarter of COUT)
#define NQ (COUT / OH)         // 4
#define TROW 9                 // padded LDS row stride (odd -> conflict-free strided reads)
#define TCT 512                // threads per tile_conv block (8 waves)

// ---------- K1: count taps per tile ----------
// Each (voxel, kk) pair produces at most one tap at output position
// q = voxel + (offset-1); the tap belongs to exactly one tile.
__global__ void tap_count_kernel(const int* __restrict__ idxs, int* __restrict__ tapcnt) {
    int idx = blockIdx.x * 256 + threadIdx.x;
    if (idx >= V_ * 27) return;
    int v = idx / 27, kk = idx - v * 27;
    int w = idxs[3 * v], h = idxs[3 * v + 1], d = idxs[3 * v + 2];
    if (!((unsigned)w < W_ && (unsigned)h < H_ && (unsigned)d < D_)) return;
    int dq = d + kk / 9 - 1;
    int hq = h + (kk / 3) % 3 - 1;
    int wq = w + kk % 3 - 1;
    if ((unsigned)dq < D_ && (unsigned)hq < H_ && (unsigned)wq < W_) {
        int tile = (dq / TD) * NTY * NTX + (hq / TH) * NTX + (wq / TW);
        atomicAdd(&tapcnt[tile], 1);
    }
}

// ---------- K2: exclusive prefix over 4096 tiles + weight transpose ----------
// wt4[((quarter*27+k)*4+jj)*8+oo] = float4{ conv_w[o][4jj+i][k] : i=0..3 }, o=quarter*8+oo
__global__ void scan_kernel(const int* __restrict__ counts, int* __restrict__ starts,
                            int* __restrict__ cursor, const float* __restrict__ conv_w,
                            float4* __restrict__ wt4) {
    __shared__ int part[256];
    int t = threadIdx.x;
    int base = t * 16;
    int s = 0;
    for (int j = 0; j < 16; ++j) s += counts[base + j];
    part[t] = s;
    __syncthreads();
    for (int off = 1; off < 256; off <<= 1) {
        int val = part[t];
        int add = (t >= off) ? part[t - off] : 0;
        __syncthreads();
        part[t] = val + add;
        __syncthreads();
    }
    int run = (t > 0) ? part[t - 1] : 0;
    for (int j = 0; j < 16; ++j) {
        starts[base + j] = run;
        cursor[base + j] = run;
        run += counts[base + j];
    }
    // weight transpose: NQ*27*4*OH = 3456 float4
    for (int n = t; n < NQ * 27 * 4 * OH; n += 256) {
        int oo = n & 7;
        int jj = (n >> 3) & 3;
        int m  = n >> 5;            // quarter*27 + k
        int k  = m % 27;
        int quarter = m / 27;
        int o = quarter * OH + oo;
        float4 wv;
        wv.x = conv_w[(o * CIN + 4 * jj + 0) * 27 + k];
        wv.y = conv_w[(o * CIN + 4 * jj + 1) * 27 + k];
        wv.z = conv_w[(o * CIN + 4 * jj + 2) * 27 + k];
        wv.w = conv_w[(o * CIN + 4 * jj + 3) * 27 + k];
        wt4[n] = wv;
    }
}

// ---------- K3: fill packed per-tile tap lists ----------
// tap word = (v<<14) | (k<<9) | pos  (v<2^16 -> fits 32b; k<27; pos<512)
__global__ void tap_fill_kernel(const int* __restrict__ idxs, int* __restrict__ cursor,
                                int* __restrict__ tapbuf) {
    int idx = blockIdx.x * 256 + threadIdx.x;
    if (idx >= V_ * 27) return;
    int v = idx / 27, kk = idx - v * 27;
    int w = idxs[3 * v], h = idxs[3 * v + 1], d = idxs[3 * v + 2];
    if (!((unsigned)w < W_ && (unsigned)h < H_ && (unsigned)d < D_)) return;
    int dq = d + kk / 9 - 1;
    int hq = h + (kk / 3) % 3 - 1;
    int wq = w + kk % 3 - 1;
    if ((unsigned)dq < D_ && (unsigned)hq < H_ && (unsigned)wq < W_) {
        int tile = (dq / TD) * NTY * NTX + (hq / TH) * NTX + (wq / TW);
        int pos = ((dq & (TD - 1)) * TH + (hq & (TH - 1))) * TW + (wq & (TW - 1));
        int k = 26 - kk;            // ((vd-dq+1)*3+(vh-hq+1))*3+(vw-wq+1) == 26-kk
        int p = atomicAdd(&cursor[tile], 1);
        tapbuf[p] = (v << 14) | (k << 9) | pos;
    }
}

// ---------- K4: feats (mean over P), indexed by voxel id directly ----------
__global__ void featpack_kernel(const float* __restrict__ vox, float4* __restrict__ feats4) {
    int idx = blockIdx.x * 256 + threadIdx.x;     // (v, chunk-of-4-channels)
    if (idx >= V_ * 4) return;
    int v = idx >> 2, q = idx & 3;
    const float* base = vox + ((size_t)v * CIN + 4 * q) * P_;
    float m[4];
#pragma unroll
    for (int c = 0; c < 4; ++c) {
        const float4* p = (const float4*)(base + c * P_);
        float s = 0.f;
#pragma unroll
        for (int j = 0; j < P_ / 4; ++j) {
            float4 t = p[j];
            s += t.x + t.y + t.z + t.w;
        }
        m[c] = s * (1.0f / (float)P_);
    }
    feats4[v * 4 + q] = make_float4(m[0], m[1], m[2], m[3]);
}

// ---------- K5: tile conv -> pre-norm output + BN stats ----------
// block = 512 = 8 channels x 64 slots; grid = (NT, 4 quarters)
// LDS ~33 KB -> 4 blocks/CU x 8 waves = 32 waves/CU (full)
__global__ void __launch_bounds__(TCT, 8) tile_conv_kernel(
    const float4* __restrict__ feats4, const float4* __restrict__ wt4,
    const int* __restrict__ tapstart, const int* __restrict__ tapcnt,
    const int* __restrict__ tapbuf, float* __restrict__ stats,
    float* __restrict__ out)
{
    __shared__ float  tile[TPOS * TROW];   // 18432 B, [pos][TROW] padded
    __shared__ float4 wsm4[27 * 4 * OH];   // 13824 B, [(k*4+jj)*8+oo]
    __shared__ float  wsum[8][OH], wsq[8][OH];

    int t = threadIdx.x;
    int tile_id = blockIdx.x;
    int quarter = blockIdx.y;
    int tx = tile_id % NTX, ty = (tile_id / NTX) % NTY, tz = tile_id / (NTX * NTY);
    int w0 = tx * TW, h0 = ty * TH, d0 = tz * TD;
    int obase = quarter * OH;

    // phase A: zero tile, stage weights, read tap segment bounds
    for (int j = t; j < TPOS * TROW / 4; j += TCT)
        ((float4*)tile)[j] = make_float4(0, 0, 0, 0);
    for (int j = t; j < 27 * 4 * OH; j += TCT)
        wsm4[j] = wt4[quarter * (27 * 4 * OH) + j];
    int gs = tapstart[tile_id];
    int nt = tapcnt[tile_id];
    __syncthreads();

    // phase C: stream taps: 4 b128 LDS weight reads + 16 FMA + ds_add per (tap, oo)
    int oo = t & 7;
    int slot = t >> 3;                      // 0..63
    for (int j = slot; j < nt; j += 64) {
        unsigned tap = (unsigned)tapbuf[gs + j];
        int pos = tap & 511;
        int k = (tap >> 9) & 31;
        int src = tap >> 14;
        const float4* fp = feats4 + src * 4;      // broadcast across 8 oo lanes
        float4 f0 = fp[0], f1 = fp[1], f2 = fp[2], f3 = fp[3];
        const float4* wp = &wsm4[(k * 4) * OH + oo];
        float4 q0 = wp[0], q1 = wp[8], q2 = wp[16], q3 = wp[24];
        float acc = q0.x * f0.x + q0.y * f0.y + q0.z * f0.z + q0.w * f0.w
                  + q1.x * f1.x + q1.y * f1.y + q1.z * f1.z + q1.w * f1.w
                  + q2.x * f2.x + q2.y * f2.y + q2.z * f2.z + q2.w * f2.w
                  + q3.x * f3.x + q3.y * f3.y + q3.z * f3.z + q3.w * f3.w;
        atomicAdd(&tile[pos * TROW + oo], acc);
    }
    __syncthreads();

    // phase D1: BN partial stats (bias cancels analytically in finalize)
    float s1 = 0.f, s2 = 0.f;
    for (int p = slot; p < TPOS; p += 64) {
        float sv = tile[p * TROW + oo];
        s1 += sv;
        s2 += sv * sv;
    }
    s1 += __shfl_xor(s1, 8);  s2 += __shfl_xor(s2, 8);
    s1 += __shfl_xor(s1, 16); s2 += __shfl_xor(s2, 16);
    s1 += __shfl_xor(s1, 32); s2 += __shfl_xor(s2, 32);
    int wave = t >> 6, lane = t & 63;
    if (lane < OH) { wsum[wave][lane] = s1; wsq[wave][lane] = s2; }

    // phase D2: write pre-norm output, coalesced; stride-9 LDS reads conflict-free
    int wl = t & 31;
    for (int r = t >> 5; r < OH * TD * TH; r += 16) {   // 128 rows, 8 iters
        int oo2 = r >> 4;          // TD*TH = 16
        int rem = r & 15;
        int pos = rem * TW + wl;
        int dl = rem >> 3, hl = rem & 7;
        out[(size_t)(obase + oo2) * DHW_ + (size_t)(d0 + dl) * HW_ +
            (size_t)(h0 + hl) * W_ + (w0 + wl)] = tile[pos * TROW + oo2];
    }
    __syncthreads();
    if (t < OH) {
        float a = 0.f, b = 0.f;
#pragma unroll
        for (int wv = 0; wv < 8; ++wv) { a += wsum[wv][t]; b += wsq[wv][t]; }
        atomicAdd(&stats[obase + t], a);
        atomicAdd(&stats[COUT + obase + t], b);
    }
}

// ---------- K6: finalize per-channel scale A and shift B ----------
__global__ void finalize_kernel(const float* __restrict__ stats,
                                const float* __restrict__ gamma,
                                const float* __restrict__ beta,
                                float* __restrict__ mi) {
    int t = threadIdx.x;
    if (t < COUT) {
        float n = (float)DHW_;
        float m1 = stats[t] / n;
        float m2 = stats[COUT + t] / n;
        float var = fmaxf(m2 - m1 * m1, 0.f);
        float inv = rsqrtf(var + EPS_);
        float A = gamma[t] * inv;
        mi[t] = A;
        mi[COUT + t] = -m1 * A + beta[t];
    }
}

// ---------- K7: in-place normalize + affine + ReLU (pure BW) ----------
__global__ void norm_kernel(float* __restrict__ out, const float* __restrict__ mi) {
    int idx4 = blockIdx.x * 256 + threadIdx.x;
    int c = idx4 >> 19;            // DHW_/4 = 2^19
    float A = mi[c], B = mi[COUT + c];
    float4 x = ((const float4*)out)[idx4];
    x.x = fmaxf(x.x * A + B, 0.f);
    x.y = fmaxf(x.y * A + B, 0.f);
    x.z = fmaxf(x.z * A + B, 0.f);
    x.w = fmaxf(x.w * A + B, 0.f);
    ((float4*)out)[idx4] = x;
}

extern "C" void kernel_launch(void* const* d_in, const int* in_sizes, int n_in,
                              void* d_out, int out_size, void* d_ws, size_t ws_size,
                              hipStream_t stream) {
    const float* voxels  = (const float*)d_in[0];
    const int*   indices = (const int*)  d_in[1];
    const float* conv_w  = (const float*)d_in[2];
    const float* gamma   = (const float*)d_in[4];
    const float* beta    = (const float*)d_in[5];
    float* out = (float*)d_out;

    float4* wt4      = (float4*)d_ws;                      // 3456 float4
    float4* feats4   = wt4 + 3456;                         // V*4 float4
    int*    tapcnt   = (int*)(feats4 + (size_t)V_ * 4);    // NT
    int*    tapstart = tapcnt + NT;                        // NT
    int*    tapcur   = tapstart + NT;                      // NT
    int*    tapbuf   = tapcur + NT;                        // V*27 = 1.08M ints
    float*  stats    = (float*)(tapbuf + (size_t)V_ * 27); // 64
    float*  mi       = stats + 2 * COUT;                   // 64

    hipMemsetAsync(tapcnt, 0, NT * sizeof(int), stream);
    hipMemsetAsync(stats, 0, 2 * COUT * sizeof(float), stream);

    const int ntap_items = V_ * 27;
    tap_count_kernel<<<(ntap_items + 255) / 256, 256, 0, stream>>>(indices, tapcnt);
    scan_kernel<<<1, 256, 0, stream>>>(tapcnt, tapstart, tapcur, conv_w, wt4);
    tap_fill_kernel<<<(ntap_items + 255) / 256, 256, 0, stream>>>(indices, tapcur, tapbuf);
    featpack_kernel<<<(V_ * 4 + 255) / 256, 256, 0, stream>>>(voxels, feats4);

    dim3 grid(NT, NQ);
    tile_conv_kernel<<<grid, TCT, 0, stream>>>(feats4, wt4, tapstart, tapcnt, tapbuf,
                                               stats, out);
    finalize_kernel<<<1, 64, 0, stream>>>(stats, gamma, beta, mi);

    const int n4 = COUT * DHW_ / 4;
    norm_kernel<<<n4 / 256, 256, 0, stream>>>(out, mi);
}

// Round 4
// 664.020 us; speedup vs baseline: 1.3155x; 1.3155x over previous
//
#include <hip/hip_runtime.h>

#define D_   32
#define H_   256
#define W_   256
#define HW_  (H_ * W_)
#define DHW_ (D_ * H_ * W_)   // 2097152
#define V_   40000
#define CIN  16
#define COUT 32
#define P_   32
#define EPS_ 1e-5f

#define TD 2
#define TH 8
#define TW 32
#define NTX (W_ / TW)          // 8
#define NTY (H_ / TH)          // 32
#define NTZ (D_ / TD)          // 16
#define NT  (NTX * NTY * NTZ)  // 4096 tiles
#define TPOS (TD * TH * TW)    // 512
#define OH 8                   // channels per block (quarter of COUT)
#define NQ (COUT / OH)         // 4
#define TROW 9                 // padded LDS row stride (odd -> conflict-free strided reads)
#define TCT 512                // threads per tile_conv block (8 waves)
#define SSLOT 64               // stats de-contention slots per channel
#define VBLK ((V_ + 255) / 256)            // 157 voxel blocks
#define WTN  (NQ * 27 * 4 * OH)            // 3456 transpose items
#define WTBLK ((WTN + 255) / 256)          // 14 transpose blocks

// ---------- K1: per-voxel tap count + weight transpose (spare blocks) ----------
__global__ void tap_count_kernel(const int* __restrict__ idxs, int* __restrict__ tapcnt,
                                 const float* __restrict__ conv_w, float4* __restrict__ wt4) {
    int b = blockIdx.x;
    if (b >= VBLK) {
        // weight transpose: wt4[((quarter*27+k)*4+jj)*8+oo] = {conv_w[o][4jj+i][k]}
        int n = (b - VBLK) * 256 + threadIdx.x;
        if (n < WTN) {
            int oo = n & 7;
            int jj = (n >> 3) & 3;
            int m  = n >> 5;            // quarter*27 + k
            int k  = m % 27;
            int quarter = m / 27;
            int o = quarter * OH + oo;
            float4 wv;
            wv.x = conv_w[(o * CIN + 4 * jj + 0) * 27 + k];
            wv.y = conv_w[(o * CIN + 4 * jj + 1) * 27 + k];
            wv.z = conv_w[(o * CIN + 4 * jj + 2) * 27 + k];
            wv.w = conv_w[(o * CIN + 4 * jj + 3) * 27 + k];
            wt4[n] = wv;
        }
        return;
    }
    int v = b * 256 + threadIdx.x;
    if (v >= V_) return;
    int w = idxs[3 * v], h = idxs[3 * v + 1], d = idxs[3 * v + 2];
    if (!((unsigned)w < W_ && (unsigned)h < H_ && (unsigned)d < D_)) return;
    int dlo = max(d - 1, 0), dhi = min(d + 1, D_ - 1);
    int hlo = max(h - 1, 0), hhi = min(h + 1, H_ - 1);
    int wlo = max(w - 1, 0), whi = min(w + 1, W_ - 1);
    for (int tz = dlo / TD; tz <= dhi / TD; ++tz) {
        int zl = max(dlo, tz * TD), zh = min(dhi, tz * TD + TD - 1);
        for (int ty = hlo / TH; ty <= hhi / TH; ++ty) {
            int yl = max(hlo, ty * TH), yh = min(hhi, ty * TH + TH - 1);
            for (int tx = wlo / TW; tx <= whi / TW; ++tx) {
                int xl = max(wlo, tx * TW), xh = min(whi, tx * TW + TW - 1);
                int cnt = (zh - zl + 1) * (yh - yl + 1) * (xh - xl + 1);
                atomicAdd(&tapcnt[tz * NTY * NTX + ty * NTX + tx], cnt);
            }
        }
    }
}

// ---------- K2: exclusive prefix over 4096 tiles ----------
__global__ void scan_kernel(const int* __restrict__ counts, int* __restrict__ starts,
                            int* __restrict__ cursor) {
    __shared__ int part[256];
    int t = threadIdx.x;
    int base = t * 16;
    int s = 0;
    for (int j = 0; j < 16; ++j) s += counts[base + j];
    part[t] = s;
    __syncthreads();
    for (int off = 1; off < 256; off <<= 1) {
        int val = part[t];
        int add = (t >= off) ? part[t - off] : 0;
        __syncthreads();
        part[t] = val + add;
        __syncthreads();
    }
    int run = (t > 0) ? part[t - 1] : 0;
    for (int j = 0; j < 16; ++j) {
        starts[base + j] = run;
        cursor[base + j] = run;
        run += counts[base + j];
    }
}

// ---------- K3: per-voxel tap fill (one cursor atomic per touched tile-region) ----------
// tap word = (v<<14) | (k<<9) | pos
__global__ void tap_fill_kernel(const int* __restrict__ idxs, int* __restrict__ cursor,
                                int* __restrict__ tapbuf) {
    int v = blockIdx.x * 256 + threadIdx.x;
    if (v >= V_) return;
    int w = idxs[3 * v], h = idxs[3 * v + 1], d = idxs[3 * v + 2];
    if (!((unsigned)w < W_ && (unsigned)h < H_ && (unsigned)d < D_)) return;
    int dlo = max(d - 1, 0), dhi = min(d + 1, D_ - 1);
    int hlo = max(h - 1, 0), hhi = min(h + 1, H_ - 1);
    int wlo = max(w - 1, 0), whi = min(w + 1, W_ - 1);
    for (int tz = dlo / TD; tz <= dhi / TD; ++tz) {
        int zl = max(dlo, tz * TD), zh = min(dhi, tz * TD + TD - 1);
        for (int ty = hlo / TH; ty <= hhi / TH; ++ty) {
            int yl = max(hlo, ty * TH), yh = min(hhi, ty * TH + TH - 1);
            for (int tx = wlo / TW; tx <= whi / TW; ++tx) {
                int xl = max(wlo, tx * TW), xh = min(whi, tx * TW + TW - 1);
                int cnt = (zh - zl + 1) * (yh - yl + 1) * (xh - xl + 1);
                int p = atomicAdd(&cursor[tz * NTY * NTX + ty * NTX + tx], cnt);
                for (int dq = zl; dq <= zh; ++dq)
                    for (int hq = yl; hq <= yh; ++hq)
                        for (int wq = xl; wq <= xh; ++wq) {
                            int k = ((d - dq + 1) * 3 + (h - hq + 1)) * 3 + (w - wq + 1);
                            int pos = ((dq & (TD - 1)) * TH + (hq & (TH - 1))) * TW
                                    + (wq & (TW - 1));
                            tapbuf[p++] = (v << 14) | (k << 9) | pos;
                        }
            }
        }
    }
}

// ---------- K4: feats (mean over P), indexed by voxel id ----------
__global__ void featpack_kernel(const float* __restrict__ vox, float4* __restrict__ feats4) {
    int idx = blockIdx.x * 256 + threadIdx.x;     // (v, chunk-of-4-channels)
    if (idx >= V_ * 4) return;
    int v = idx >> 2, q = idx & 3;
    const float* base = vox + ((size_t)v * CIN + 4 * q) * P_;
    float m[4];
#pragma unroll
    for (int c = 0; c < 4; ++c) {
        const float4* p = (const float4*)(base + c * P_);
        float s = 0.f;
#pragma unroll
        for (int j = 0; j < P_ / 4; ++j) {
            float4 t = p[j];
            s += t.x + t.y + t.z + t.w;
        }
        m[c] = s * (1.0f / (float)P_);
    }
    feats4[v * 4 + q] = make_float4(m[0], m[1], m[2], m[3]);
}

// ---------- K5: tile conv -> pre-norm output + BN stats ----------
// block = 512 = 8 channels x 64 slots; grid = (NT, 4 quarters)
// LDS ~33 KB -> 4 blocks/CU x 8 waves = 32 waves/CU
__global__ void __launch_bounds__(TCT, 8) tile_conv_kernel(
    const float4* __restrict__ feats4, const float4* __restrict__ wt4,
    const int* __restrict__ tapstart, const int* __restrict__ tapcnt,
    const int* __restrict__ tapbuf, float* __restrict__ stats,
    float* __restrict__ out)
{
    __shared__ float  tile[TPOS * TROW];   // 18432 B
    __shared__ float4 wsm4[27 * 4 * OH];   // 13824 B
    __shared__ float  wsum[8][OH], wsq[8][OH];

    int t = threadIdx.x;
    int tile_id = blockIdx.x;
    int quarter = blockIdx.y;
    int gs = tapstart[tile_id];
    int nt = tapcnt[tile_id];
    int tx = tile_id % NTX, ty = (tile_id / NTX) % NTY, tz = tile_id / (NTX * NTY);
    int w0 = tx * TW, h0 = ty * TH, d0 = tz * TD;
    int obase = quarter * OH;

    // phase A: zero tile, stage weights
    for (int j = t; j < TPOS * TROW / 4; j += TCT)
        ((float4*)tile)[j] = make_float4(0, 0, 0, 0);
    for (int j = t; j < 27 * 4 * OH; j += TCT)
        wsm4[j] = wt4[quarter * (27 * 4 * OH) + j];
    __syncthreads();

    // phase C: stream taps, software-pipelined (prefetch next tap + its feats)
    int oo = t & 7;
    int slot = t >> 3;                      // 0..63
    int j = slot;
    if (j < nt) {
        unsigned tap = (unsigned)tapbuf[gs + j];
        const float4* fp = feats4 + (size_t)(tap >> 14) * 4;
        float4 f0 = fp[0], f1 = fp[1], f2 = fp[2], f3 = fp[3];
        while (true) {
            int jn = j + 64;
            bool more = jn < nt;
            unsigned tapn = 0u;
            float4 g0, g1, g2, g3;
            if (more) {
                tapn = (unsigned)tapbuf[gs + jn];
                const float4* gp = feats4 + (size_t)(tapn >> 14) * 4;
                g0 = gp[0]; g1 = gp[1]; g2 = gp[2]; g3 = gp[3];
            }
            int pos = tap & 511;
            int k = (tap >> 9) & 31;
            const float4* wp = &wsm4[(k * 4) * OH + oo];
            float4 q0 = wp[0], q1 = wp[8], q2 = wp[16], q3 = wp[24];
            float acc = q0.x * f0.x + q0.y * f0.y + q0.z * f0.z + q0.w * f0.w
                      + q1.x * f1.x + q1.y * f1.y + q1.z * f1.z + q1.w * f1.w
                      + q2.x * f2.x + q2.y * f2.y + q2.z * f2.z + q2.w * f2.w
                      + q3.x * f3.x + q3.y * f3.y + q3.z * f3.z + q3.w * f3.w;
            atomicAdd(&tile[pos * TROW + oo], acc);
            if (!more) break;
            tap = tapn; f0 = g0; f1 = g1; f2 = g2; f3 = g3; j = jn;
        }
    }
    __syncthreads();

    // phase D1: BN partial stats
    float s1 = 0.f, s2 = 0.f;
    for (int p = slot; p < TPOS; p += 64) {
        float sv = tile[p * TROW + oo];
        s1 += sv;
        s2 += sv * sv;
    }
    s1 += __shfl_xor(s1, 8);  s2 += __shfl_xor(s2, 8);
    s1 += __shfl_xor(s1, 16); s2 += __shfl_xor(s2, 16);
    s1 += __shfl_xor(s1, 32); s2 += __shfl_xor(s2, 32);
    int wave = t >> 6, lane = t & 63;
    if (lane < OH) { wsum[wave][lane] = s1; wsq[wave][lane] = s2; }

    // phase D2: write pre-norm output, coalesced; stride-9 LDS reads conflict-free
    int wl = t & 31;
    for (int r = t >> 5; r < OH * TD * TH; r += 16) {   // 128 rows, 8 iters
        int oo2 = r >> 4;
        int rem = r & 15;
        int pos = rem * TW + wl;
        int dl = rem >> 3, hl = rem & 7;
        out[(size_t)(obase + oo2) * DHW_ + (size_t)(d0 + dl) * HW_ +
            (size_t)(h0 + hl) * W_ + (w0 + wl)] = tile[pos * TROW + oo2];
    }
    __syncthreads();
    if (t < OH) {
        float a = 0.f, b = 0.f;
#pragma unroll
        for (int wv = 0; wv < 8; ++wv) { a += wsum[wv][t]; b += wsq[wv][t]; }
        int sl = tile_id & (SSLOT - 1);
        atomicAdd(&stats[(obase + t) * SSLOT + sl], a);
        atomicAdd(&stats[COUT * SSLOT + (obase + t) * SSLOT + sl], b);
    }
}

// ---------- K6: finalize per-channel scale A and shift B ----------
__global__ void finalize_kernel(const float* __restrict__ stats,
                                const float* __restrict__ gamma,
                                const float* __restrict__ beta,
                                float* __restrict__ mi) {
    int t = threadIdx.x;
    if (t < COUT) {
        float m1 = 0.f, m2 = 0.f;
        for (int s = 0; s < SSLOT; ++s) {
            m1 += stats[t * SSLOT + s];
            m2 += stats[COUT * SSLOT + t * SSLOT + s];
        }
        float n = (float)DHW_;
        m1 /= n;
        m2 /= n;
        float var = fmaxf(m2 - m1 * m1, 0.f);
        float inv = rsqrtf(var + EPS_);
        float A = gamma[t] * inv;
        mi[t] = A;
        mi[COUT + t] = -m1 * A + beta[t];
    }
}

// ---------- K7: in-place normalize + affine + ReLU (pure BW) ----------
__global__ void norm_kernel(float* __restrict__ out, const float* __restrict__ mi) {
    int idx4 = blockIdx.x * 256 + threadIdx.x;
    int c = idx4 >> 19;            // DHW_/4 = 2^19
    float A = mi[c], B = mi[COUT + c];
    float4 x = ((const float4*)out)[idx4];
    x.x = fmaxf(x.x * A + B, 0.f);
    x.y = fmaxf(x.y * A + B, 0.f);
    x.z = fmaxf(x.z * A + B, 0.f);
    x.w = fmaxf(x.w * A + B, 0.f);
    ((float4*)out)[idx4] = x;
}

extern "C" void kernel_launch(void* const* d_in, const int* in_sizes, int n_in,
                              void* d_out, int out_size, void* d_ws, size_t ws_size,
                              hipStream_t stream) {
    const float* voxels  = (const float*)d_in[0];
    const int*   indices = (const int*)  d_in[1];
    const float* conv_w  = (const float*)d_in[2];
    const float* gamma   = (const float*)d_in[4];
    const float* beta    = (const float*)d_in[5];
    float* out = (float*)d_out;

    // Workspace layout: small fixed arrays FIRST, variable-use tapbuf LAST.
    // Written extent <= 2,681,088 + 4*T bytes (T ~ 1.05M actual taps) ~ 6.89 MB,
    // below the R2-proven 6.98 MB high-water mark. (R3 failed because a 16 KB
    // stats region at the tail pushed writes past ws_size, corrupting an
    // adjacent input allocation -> calls after the first read poisoned inputs.)
    float4* wt4      = (float4*)d_ws;                        // 3456 float4 (55,296 B)
    float*  stats    = (float*)(wt4 + WTN);                  // 2*COUT*SSLOT floats (16,384 B)
    float*  mi       = stats + 2 * COUT * SSLOT;             // 64 floats (256 B)
    int*    tapcnt   = (int*)(mi + 2 * COUT);                // NT ints
    int*    tapstart = tapcnt + NT;                          // NT ints
    int*    tapcur   = tapstart + NT;                        // NT ints
    float4* feats4   = (float4*)(tapcur + NT);               // V*4 float4 (2.56 MB), 16B-aligned
    int*    tapbuf   = (int*)(feats4 + (size_t)V_ * 4);      // <= V*27 ints, only prefix used

    hipMemsetAsync(tapcnt, 0, NT * sizeof(int), stream);
    hipMemsetAsync(stats, 0, 2 * COUT * SSLOT * sizeof(float), stream);

    tap_count_kernel<<<VBLK + WTBLK, 256, 0, stream>>>(indices, tapcnt, conv_w, wt4);
    scan_kernel<<<1, 256, 0, stream>>>(tapcnt, tapstart, tapcur);
    tap_fill_kernel<<<VBLK, 256, 0, stream>>>(indices, tapcur, tapbuf);
    featpack_kernel<<<(V_ * 4 + 255) / 256, 256, 0, stream>>>(voxels, feats4);

    dim3 grid(NT, NQ);
    tile_conv_kernel<<<grid, TCT, 0, stream>>>(feats4, wt4, tapstart, tapcnt, tapbuf,
                                               stats, out);
    finalize_kernel<<<1, 64, 0, stream>>>(stats, gamma, beta, mi);

    const int n4 = COUT * DHW_ / 4;
    norm_kernel<<<n4 / 256, 256, 0, stream>>>(out, mi);
}